// Round 9
// baseline (131.502 us; speedup 1.0000x reference)
//
#include <hip/hip_runtime.h>
#include <math.h>

// Problem constants: B=512, Q=100, C=81, V=117
#define Bn 512
#define Qn 100
#define Cn 81
#define Vn 117
#define NQ (Bn * Qn)            // 51200

// d_out layout (floats), outputs concatenated flat in return order:
// hoi_scores (B,Q,V) | obj_labels (B,Q) | sub_boxes (B,Q,4) | obj_boxes (B,Q,4) | keep (B,Q)
#define OFF_HOI  0
#define OFF_LAB  (NQ * Vn)
#define OFF_SUB  (OFF_LAB + NQ)
#define OFF_OBJ  (OFF_SUB + NQ * 4)
#define OFF_KEEP (OFF_OBJ + NQ * 4)

// d_ws layout (bytes): [0, 38K) cmT | [64K, +~820K) ROW masks | then order map
#define WS_ROW_OFF  65536
#define WS_OI_OFF   (WS_ROW_OFF + Bn * Qn * 2 * 8)   // Bn*Qn ints

__device__ __forceinline__ float frcp(float x) { return __builtin_amdgcn_rcpf(x); }

// --- tiny transpose: cmT[c*V + v] = cm[v*C + c] (global, stays L2-hot) ---
__global__ __launch_bounds__(128) void cm_transpose(const float* __restrict__ cm,
                                                    float* __restrict__ cmT) {
    int c = blockIdx.x;      // 0..80
    int v = threadIdx.x;     // 0..127
    if (v < Vn) cmT[c * Vn + v] = cm[v * Cn + c];
}

// --- K1: 16 consecutive items per 256-thr block; slabs staged via float4.
__global__ __launch_bounds__(256) void hoi_k1(
    const float* __restrict__ obj_logits,
    const float* __restrict__ verb_logits,
    const float* __restrict__ sub_boxes,
    const float* __restrict__ obj_boxes,
    const float* __restrict__ cmT,          // transposed correct_mat (C x V)
    const int*   __restrict__ target_sizes,
    float* __restrict__ out)
{
    __shared__ float L[16 * Cn];            // 1296 floats
    __shared__ float W[16 * Vn];            // 1872 floats

    const int tid  = threadIdx.x;
    const int base = blockIdx.x * 16;       // first item of slab, grid = NQ/16
    const int t    = tid & 15;              // lane within 16-lane group
    const int g    = tid >> 4;              // group 0..15
    const int idx  = base + g;
    const int b    = idx / Qn;

    // ---- stage slabs, block-coalesced float4 ----------------------------
    {
        const float4* lgs = (const float4*)(obj_logits + (size_t)base * Cn);
        float4* Lv = (float4*)L;
        for (int i = tid; i < (16 * Cn) / 4; i += 256) Lv[i] = lgs[i];
        const float4* vls = (const float4*)(verb_logits + (size_t)base * Vn);
        float4* Wv = (float4*)W;
        for (int i = tid; i < (16 * Vn) / 4; i += 256) Wv[i] = vls[i];
    }
    __syncthreads();

    // ---- obj softmax from LDS: cols 0..79 in 5 chunks, col 80 broadcast -
    const float* lg = L + g * Cn;
    float l0 = lg[t], l1 = lg[t + 16], l2 = lg[t + 32], l3 = lg[t + 48], l4 = lg[t + 64];
    float l5 = lg[80];

    // argmax over cols [0,80): local scan keeps lowest col on tie
    float v = l0; int vid = t;
    if (l1 > v) { v = l1; vid = t + 16; }
    if (l2 > v) { v = l2; vid = t + 32; }
    if (l3 > v) { v = l3; vid = t + 48; }
    if (l4 > v) { v = l4; vid = t + 64; }
    #pragma unroll
    for (int o = 8; o; o >>= 1) {
        float ov = __shfl_xor(v, o, 64);
        int   oi = __shfl_xor(vid, o, 64);
        if (ov > v || (ov == v && oi < vid)) { v = ov; vid = oi; }
    }

    // sum(exp) over all 81 (no max-subtract: logits ~N(0,1), exp safe)
    float e = __expf(l0) + __expf(l1) + __expf(l2) + __expf(l3) + __expf(l4);
    #pragma unroll
    for (int o = 8; o; o >>= 1) e += __shfl_xor(e, o, 64);
    e += __expf(l5);

    const int   label     = vid;            // group-uniform after reduction
    const float obj_score = __expf(v) * frcp(e);

    // ---- verb sigmoid * obj_score * mask; write back into LDS slab ------
    float* vrow = W + g * Vn;
    const float* crow = cmT + (size_t)label * Vn;   // global, L2-hot, coalesced

    float mx = 0.f;
    #pragma unroll
    for (int c = 0; c < 8; c++) {           // chunks 0..6 full, 7 partial (t<5)
        int col = t + 16 * c;
        if (col < Vn) {
            float x = vrow[col];
            float h = frcp(1.f + __expf(-x)) * obj_score * crow[col];
            vrow[col] = h;
            mx = fmaxf(mx, h);
        }
    }
    #pragma unroll
    for (int o = 8; o; o >>= 1) mx = fmaxf(mx, __shfl_xor(mx, o, 64));

    if (t == 0) {
        out[OFF_LAB + idx]  = (float)label;
        out[OFF_KEEP + idx] = mx;           // temp stash of max_scores
    }

    // ---- boxes: cxcywh -> xyxy, scaled by (w,h,w,h) ---------------------
    if (t < 2) {
        float ih = (float)target_sizes[2 * b + 0];
        float iw = (float)target_sizes[2 * b + 1];
        const float4 bx = ((const float4*)(t == 0 ? sub_boxes : obj_boxes))[idx];
        float4 r;
        r.x = (bx.x - 0.5f * bx.z) * iw;
        r.y = (bx.y - 0.5f * bx.w) * ih;
        r.z = (bx.x + 0.5f * bx.z) * iw;
        r.w = (bx.y + 0.5f * bx.w) * ih;
        ((float4*)(out + (t == 0 ? OFF_SUB : OFF_OBJ)))[idx] = r;
    }
    __syncthreads();

    // ---- store hoi slab, block-coalesced float4 -------------------------
    {
        const float4* Wv = (const float4*)W;
        float4* ho = (float4*)(out + OFF_HOI + (size_t)base * Vn);
        for (int i = tid; i < (16 * Vn) / 4; i += 256) ho[i] = Wv[i];
    }
}

// --- NMS stage 1 (fused sort+matrix): grid = 8*512 blocks of 128 ---------
// g = blockIdx >> 9 (row group, 13 rows), b = blockIdx & 511 (image).
// Every block independently rank-sorts its image in LDS (deterministic, so
// all 8 groups agree), then builds its 13 suppression-matrix rows via
// __ballot. Group 0 also emits the sorted->original index map for stage 2.
__global__ __launch_bounds__(128) void nms_mat(const float* __restrict__ out,
                                               unsigned long long* __restrict__ roww,
                                               int* __restrict__ oiws)
{
    __shared__ float  sc[Qn];
    __shared__ float4 SB[Qn], OB[Qn], MT[Qn];   // sorted boxes + meta
    __shared__ int    OI[Qn];

    const int g = blockIdx.x >> 9;
    const int b = blockIdx.x & 511;
    const int t = threadIdx.x;              // col j = t
    const int sub  = t >> 6;                // wave 0: cols 0..63, wave 1: 64..127
    const int lane = t & 63;
    const bool jv  = (t < Qn);

    // prefetch all inputs up front; latency overlaps the rank loop
    float  kv = 0.f, labf = 0.f;
    float4 sb = make_float4(0.f,0.f,0.f,0.f), ob = sb;
    if (jv) {
        kv   = out[OFF_KEEP + b * Qn + t];
        sb   = ((const float4*)(out + OFF_SUB))[b * Qn + t];
        ob   = ((const float4*)(out + OFF_OBJ))[b * Qn + t];
        labf = out[OFF_LAB + b * Qn + t];
        sc[t] = kv;
    }
    __syncthreads();

    if (jv) {
        int r = 0;
        #pragma unroll 4
        for (int j = 0; j < Qn; j++) {
            float sj = sc[j];
            r += (sj > kv) || (sj == kv && j < t);
        }
        SB[r] = sb; OB[r] = ob;
        MT[r] = make_float4(
            (sb.z - sb.x + 1.f) * (sb.w - sb.y + 1.f),
            (ob.z - ob.x + 1.f) * (ob.w - ob.y + 1.f),
            labf, 0.f);
        OI[r] = t;
    }
    __syncthreads();

    float4 js = make_float4(0.f,0.f,0.f,0.f), jo = js, jm = js;
    if (jv) { js = SB[t]; jo = OB[t]; jm = MT[t]; }

    const int i0 = g * 13;
    const int i1 = (i0 + 13 < Qn - 1) ? i0 + 13 : Qn - 1;   // rows 0..98
    unsigned long long* rw = roww + ((size_t)b * Qn) * 2;

    for (int i = i0; i < i1; i++) {
        float4 is = SB[i], io = OB[i], im = MT[i];   // LDS broadcast
        float ww = fmaxf(0.f, fminf(is.z, js.z) - fmaxf(is.x, js.x) + 1.f);
        float hh = fmaxf(0.f, fminf(is.w, js.w) - fmaxf(is.y, js.y) + 1.f);
        float inter = ww * hh;
        float iou_s = inter / (im.x + jm.x - inter);
        ww = fmaxf(0.f, fminf(io.z, jo.z) - fmaxf(io.x, jo.x) + 1.f);
        hh = fmaxf(0.f, fminf(io.w, jo.w) - fmaxf(io.y, jo.y) + 1.f);
        inter = ww * hh;
        float iou_o = inter / (im.y + jm.y - inter);
        bool cond = jv && (t > i) && (jm.z == im.z) && (iou_s * sqrtf(iou_o) > 0.7f);
        unsigned long long m = __ballot(cond);
        if (lane == 0) rw[2 * i + sub] = m;
    }

    if (g == 0 && jv) oiws[b * Qn + t] = OI[t];   // order map for stage 2
}

// --- NMS stage 2: serial greedy bitmask scan + scatter, 1 wave per image -
__global__ __launch_bounds__(64) void nms_chain(const ulonglong2* __restrict__ roww2,
                                                const int* __restrict__ oiws,
                                                float* __restrict__ out)
{
    __shared__ ulonglong2 R[Qn];            // rows 0..98 used (99 = garbage, unread)
    __shared__ int oi[Qn];
    const int b = blockIdx.x;
    const int l = threadIdx.x;              // 0..63

    const ulonglong2* rw = roww2 + (size_t)b * Qn;
    const int*        om = oiws + b * Qn;

    R[l] = rw[l];
    oi[l] = om[l];
    if (l < 36) { R[64 + l] = rw[64 + l]; oi[64 + l] = om[64 + l]; }
    __syncthreads();

    unsigned long long s0 = 0ull, s1 = 0ull;
    for (int k = 0; k < Qn - 1; k++) {
        unsigned long long dead = ((k < 64 ? s0 : s1) >> (k & 63)) & 1ull;
        if (!dead) { ulonglong2 r = R[k]; s0 |= r.x; s1 |= r.y; }
    }

    float* keepp = out + OFF_KEEP + (size_t)b * Qn;
    keepp[oi[l]] = ((s0 >> l) & 1ull) ? 0.f : 1.f;
    if (l < 36) keepp[oi[64 + l]] = ((s1 >> l) & 1ull) ? 0.f : 1.f;
}

extern "C" void kernel_launch(void* const* d_in, const int* in_sizes, int n_in,
                              void* d_out, int out_size, void* d_ws, size_t ws_size,
                              hipStream_t stream) {
    const float* obj_logits   = (const float*)d_in[0];
    const float* verb_logits  = (const float*)d_in[1];
    const float* sub_boxes    = (const float*)d_in[2];
    const float* obj_boxes    = (const float*)d_in[3];
    const float* correct_mat  = (const float*)d_in[4];
    const int*   target_sizes = (const int*)d_in[5];
    float* out = (float*)d_out;

    float*              cmT  = (float*)d_ws;
    unsigned long long* roww = (unsigned long long*)((char*)d_ws + WS_ROW_OFF);
    int*                oiws = (int*)((char*)d_ws + WS_OI_OFF);

    cm_transpose<<<Cn, 128, 0, stream>>>(correct_mat, cmT);
    hoi_k1<<<NQ / 16, 256, 0, stream>>>(obj_logits, verb_logits, sub_boxes,
                                        obj_boxes, cmT, target_sizes, out);
    nms_mat<<<8 * Bn, 128, 0, stream>>>(out, roww, oiws);
    nms_chain<<<Bn, 64, 0, stream>>>((const ulonglong2*)roww, oiws, out);
}

// Round 10
// 130.271 us; speedup vs baseline: 1.0095x; 1.0095x over previous
//
#include <hip/hip_runtime.h>
#include <math.h>

// Problem constants: B=512, Q=100, C=81, V=117
#define Bn 512
#define Qn 100
#define Cn 81
#define Vn 117
#define NQ (Bn * Qn)            // 51200

// d_out layout (floats), outputs concatenated flat in return order:
// hoi_scores (B,Q,V) | obj_labels (B,Q) | sub_boxes (B,Q,4) | obj_boxes (B,Q,4) | keep (B,Q)
#define OFF_HOI  0
#define OFF_LAB  (NQ * Vn)
#define OFF_SUB  (OFF_LAB + NQ)
#define OFF_OBJ  (OFF_SUB + NQ * 4)
#define OFF_KEEP (OFF_OBJ + NQ * 4)

// d_ws layout (bytes): [0, 38K) cmT | [64K, +2.4M) SRT | then ROW masks
#define WS_SRT_OFF  65536
#define WS_ROW_OFF  (65536 + Bn * 300 * 16)   // SRT = 300 float4 per image

__device__ __forceinline__ float frcp(float x) { return __builtin_amdgcn_rcpf(x); }

// --- tiny transpose: cmT[c*V + v] = cm[v*C + c] (global, stays L2-hot) ---
__global__ __launch_bounds__(128) void cm_transpose(const float* __restrict__ cm,
                                                    float* __restrict__ cmT) {
    int c = blockIdx.x;      // 0..80
    int v = threadIdx.x;     // 0..127
    if (v < Vn) cmT[c * Vn + v] = cm[v * Cn + c];
}

// --- K1: 16 consecutive items per 256-thr block; slabs staged via float4.
__global__ __launch_bounds__(256) void hoi_k1(
    const float* __restrict__ obj_logits,
    const float* __restrict__ verb_logits,
    const float* __restrict__ sub_boxes,
    const float* __restrict__ obj_boxes,
    const float* __restrict__ cmT,          // transposed correct_mat (C x V)
    const int*   __restrict__ target_sizes,
    float* __restrict__ out)
{
    __shared__ float L[16 * Cn];            // 1296 floats
    __shared__ float W[16 * Vn];            // 1872 floats

    const int tid  = threadIdx.x;
    const int base = blockIdx.x * 16;       // first item of slab, grid = NQ/16
    const int t    = tid & 15;              // lane within 16-lane group
    const int g    = tid >> 4;              // group 0..15
    const int idx  = base + g;
    const int b    = idx / Qn;

    // ---- stage slabs, block-coalesced float4 ----------------------------
    {
        const float4* lgs = (const float4*)(obj_logits + (size_t)base * Cn);
        float4* Lv = (float4*)L;
        for (int i = tid; i < (16 * Cn) / 4; i += 256) Lv[i] = lgs[i];
        const float4* vls = (const float4*)(verb_logits + (size_t)base * Vn);
        float4* Wv = (float4*)W;
        for (int i = tid; i < (16 * Vn) / 4; i += 256) Wv[i] = vls[i];
    }
    __syncthreads();

    // ---- obj softmax from LDS: cols 0..79 in 5 chunks, col 80 broadcast -
    const float* lg = L + g * Cn;
    float l0 = lg[t], l1 = lg[t + 16], l2 = lg[t + 32], l3 = lg[t + 48], l4 = lg[t + 64];
    float l5 = lg[80];

    // argmax over cols [0,80): local scan keeps lowest col on tie
    float v = l0; int vid = t;
    if (l1 > v) { v = l1; vid = t + 16; }
    if (l2 > v) { v = l2; vid = t + 32; }
    if (l3 > v) { v = l3; vid = t + 48; }
    if (l4 > v) { v = l4; vid = t + 64; }
    #pragma unroll
    for (int o = 8; o; o >>= 1) {
        float ov = __shfl_xor(v, o, 64);
        int   oi = __shfl_xor(vid, o, 64);
        if (ov > v || (ov == v && oi < vid)) { v = ov; vid = oi; }
    }

    // sum(exp) over all 81 (no max-subtract: logits ~N(0,1), exp safe)
    float e = __expf(l0) + __expf(l1) + __expf(l2) + __expf(l3) + __expf(l4);
    #pragma unroll
    for (int o = 8; o; o >>= 1) e += __shfl_xor(e, o, 64);
    e += __expf(l5);

    const int   label     = vid;            // group-uniform after reduction
    const float obj_score = __expf(v) * frcp(e);

    // ---- verb sigmoid * obj_score * mask; write back into LDS slab ------
    float* vrow = W + g * Vn;
    const float* crow = cmT + (size_t)label * Vn;   // global, L2-hot, coalesced

    float mx = 0.f;
    #pragma unroll
    for (int c = 0; c < 8; c++) {           // chunks 0..6 full, 7 partial (t<5)
        int col = t + 16 * c;
        if (col < Vn) {
            float x = vrow[col];
            float h = frcp(1.f + __expf(-x)) * obj_score * crow[col];
            vrow[col] = h;
            mx = fmaxf(mx, h);
        }
    }
    #pragma unroll
    for (int o = 8; o; o >>= 1) mx = fmaxf(mx, __shfl_xor(mx, o, 64));

    if (t == 0) {
        out[OFF_LAB + idx]  = (float)label;
        out[OFF_KEEP + idx] = mx;           // temp stash of max_scores
    }

    // ---- boxes: cxcywh -> xyxy, scaled by (w,h,w,h) ---------------------
    if (t < 2) {
        float ih = (float)target_sizes[2 * b + 0];
        float iw = (float)target_sizes[2 * b + 1];
        const float4 bx = ((const float4*)(t == 0 ? sub_boxes : obj_boxes))[idx];
        float4 r;
        r.x = (bx.x - 0.5f * bx.z) * iw;
        r.y = (bx.y - 0.5f * bx.w) * ih;
        r.z = (bx.x + 0.5f * bx.z) * iw;
        r.w = (bx.y + 0.5f * bx.w) * ih;
        ((float4*)(out + (t == 0 ? OFF_SUB : OFF_OBJ)))[idx] = r;
    }
    __syncthreads();

    // ---- store hoi slab, block-coalesced float4 -------------------------
    {
        const float4* Wv = (const float4*)W;
        float4* ho = (float4*)(out + OFF_HOI + (size_t)base * Vn);
        for (int i = tid; i < (16 * Vn) / 4; i += 256) ho[i] = Wv[i];
    }
}

// --- NMS stage 1: stable rank sort; sorted arrays -> ws SRT --------------
// SRT per image: [0,100) sub float4 | [100,200) obj float4 |
//                [200,300) meta {sarea, oarea, label, orig_idx}
__global__ __launch_bounds__(128) void nms_sort(const float* __restrict__ out,
                                                float4* __restrict__ srt)
{
    __shared__ float sc[Qn];
    const int b = blockIdx.x;
    const int t = threadIdx.x;

    // prefetch everything up front; latency overlaps the rank loop
    float  kv = 0.f, labf = 0.f;
    float4 sb = make_float4(0.f,0.f,0.f,0.f), ob = sb;
    if (t < Qn) {
        kv   = out[OFF_KEEP + b * Qn + t];
        sb   = ((const float4*)(out + OFF_SUB))[b * Qn + t];
        ob   = ((const float4*)(out + OFF_OBJ))[b * Qn + t];
        labf = out[OFF_LAB + b * Qn + t];
        sc[t] = kv;
    }
    __syncthreads();

    if (t < Qn) {
        int r = 0;
        #pragma unroll 4
        for (int j = 0; j < Qn; j++) {
            float sj = sc[j];
            r += (sj > kv) || (sj == kv && j < t);
        }
        float4* S = srt + (size_t)b * 300;
        S[r]           = sb;
        S[100 + r]     = ob;
        S[200 + r]     = make_float4(
            (sb.z - sb.x + 1.f) * (sb.w - sb.y + 1.f),
            (ob.z - ob.x + 1.f) * (ob.w - ob.y + 1.f),
            labf, (float)t);
    }
}

// --- NMS stage 2: suppression-matrix rows via ballot ---------------------
// grid = 8 * 512: g = blockIdx >> 9 (row group), b = blockIdx & 511 (image)
// Block 128 thr = 2 waves; thread t = sorted column j; rows i in [13g, 13g+13).
__global__ __launch_bounds__(128) void nms_mat(const float4* __restrict__ srt,
                                               unsigned long long* __restrict__ roww)
{
    const int g = blockIdx.x >> 9;
    const int b = blockIdx.x & 511;
    const int t = threadIdx.x;              // col j = t
    const int sub  = t >> 6;                // wave 0: cols 0..63, wave 1: 64..127
    const int lane = t & 63;
    const bool jv  = (t < Qn);

    const float4* S = srt + (size_t)b * 300;
    float4 js = make_float4(0.f,0.f,0.f,0.f), jo = js, jm = js;
    if (jv) { js = S[t]; jo = S[100 + t]; jm = S[200 + t]; }

    const int i0 = g * 13;
    const int i1 = (i0 + 13 < Qn - 1) ? i0 + 13 : Qn - 1;   // rows 0..98
    unsigned long long* rw = roww + ((size_t)b * Qn) * 2;

    for (int i = i0; i < i1; i++) {
        float4 is = S[i], io = S[100 + i], im = S[200 + i];  // uniform -> s_load
        float ww = fmaxf(0.f, fminf(is.z, js.z) - fmaxf(is.x, js.x) + 1.f);
        float hh = fmaxf(0.f, fminf(is.w, js.w) - fmaxf(is.y, js.y) + 1.f);
        float inter = ww * hh;
        float iou_s = inter / (im.x + jm.x - inter);
        ww = fmaxf(0.f, fminf(io.z, jo.z) - fmaxf(io.x, jo.x) + 1.f);
        hh = fmaxf(0.f, fminf(io.w, jo.w) - fmaxf(io.y, jo.y) + 1.f);
        inter = ww * hh;
        float iou_o = inter / (im.y + jm.y - inter);
        bool cond = jv && (t > i) && (jm.z == im.z) && (iou_s * sqrtf(iou_o) > 0.7f);
        unsigned long long m = __ballot(cond);
        if (lane == 0) rw[2 * i + sub] = m;
    }
}

// --- NMS stage 3: serial greedy bitmask scan + scatter, 1 wave per image -
__global__ __launch_bounds__(64) void nms_chain(const float4* __restrict__ srt,
                                                const ulonglong2* __restrict__ roww2,
                                                float* __restrict__ out)
{
    __shared__ ulonglong2 R[Qn];            // rows 0..98 used (99 = garbage, unread)
    __shared__ int oi[Qn];
    const int b = blockIdx.x;
    const int l = threadIdx.x;              // 0..63

    const ulonglong2* rw = roww2 + (size_t)b * Qn;
    const float4*     M  = srt + (size_t)b * 300 + 200;

    R[l] = rw[l];
    oi[l] = (int)M[l].w;
    if (l < 36) { R[64 + l] = rw[64 + l]; oi[64 + l] = (int)M[64 + l].w; }
    __syncthreads();

    unsigned long long s0 = 0ull, s1 = 0ull;
    for (int k = 0; k < Qn - 1; k++) {
        unsigned long long dead = ((k < 64 ? s0 : s1) >> (k & 63)) & 1ull;
        if (!dead) { ulonglong2 r = R[k]; s0 |= r.x; s1 |= r.y; }
    }

    float* keepp = out + OFF_KEEP + (size_t)b * Qn;
    keepp[oi[l]] = ((s0 >> l) & 1ull) ? 0.f : 1.f;
    if (l < 36) keepp[oi[64 + l]] = ((s1 >> l) & 1ull) ? 0.f : 1.f;
}

extern "C" void kernel_launch(void* const* d_in, const int* in_sizes, int n_in,
                              void* d_out, int out_size, void* d_ws, size_t ws_size,
                              hipStream_t stream) {
    const float* obj_logits   = (const float*)d_in[0];
    const float* verb_logits  = (const float*)d_in[1];
    const float* sub_boxes    = (const float*)d_in[2];
    const float* obj_boxes    = (const float*)d_in[3];
    const float* correct_mat  = (const float*)d_in[4];
    const int*   target_sizes = (const int*)d_in[5];
    float* out = (float*)d_out;

    float*              cmT  = (float*)d_ws;
    float4*             srt  = (float4*)((char*)d_ws + WS_SRT_OFF);
    unsigned long long* roww = (unsigned long long*)((char*)d_ws + WS_ROW_OFF);

    cm_transpose<<<Cn, 128, 0, stream>>>(correct_mat, cmT);
    hoi_k1<<<NQ / 16, 256, 0, stream>>>(obj_logits, verb_logits, sub_boxes,
                                        obj_boxes, cmT, target_sizes, out);
    nms_sort<<<Bn, 128, 0, stream>>>(out, srt);
    nms_mat<<<8 * Bn, 128, 0, stream>>>(srt, roww);
    nms_chain<<<Bn, 64, 0, stream>>>(srt, (const ulonglong2*)roww, out);
}